// Round 4
// baseline (1985.765 us; speedup 1.0000x reference)
//
#include <hip/hip_runtime.h>
#include <hip/hip_bf16.h>
#include <hip/hip_fp16.h>

#define N_NODES 50000
#define N_EDGES 800000
#define DD 96
#define NLAYER 4
#define N_GRAPHS 256
#define BN_EPS 1e-5f
#define SLABS 8
#define SFEAT 12  // features (halfs) per slab; SLABS*SFEAT = 96

// ---------------- workspace layout (units: 4-byte elements) ----------------
enum : size_t {
  O_CNT    = 0,                        // int[N_NODES]
  O_STATS  = O_CNT + N_NODES,          // float[4*192]  (sum, sumsq per layer)
  O_POOL   = O_STATS + 4 * 192,        // float[N_GRAPHS*96]
  O_GCNT   = O_POOL + N_GRAPHS * DD,   // int[N_GRAPHS]
  ZERO_END = O_GCNT + N_GRAPHS,
  O_ROWPTR = ZERO_END,                 // int[N_NODES+1]
  O_DIS    = O_ROWPTR + N_NODES + 1,   // float[N_NODES]
  O_BSUMS  = O_DIS + N_NODES,          // int[256]
  O_EDGE   = O_BSUMS + 256,            // uint[N_EDGES]: src | half(w)<<16
  O_HWH    = (O_EDGE + N_EDGES + 3) & ~size_t(3),  // half[8][50000][12] = 9.6 MB
  O_P      = O_HWH + (size_t)SLABS * N_NODES * SFEAT / 2,  // float[N_NODES*96] agg
  WS_ELEMS = O_P + (size_t)N_NODES * DD
};

__device__ __forceinline__ void atomAddF(float* p, float v) {
  unsafeAtomicAdd(p, v);  // native fp32 atomic add
}

__device__ __forceinline__ float2 h2f(unsigned int u) {
  __half2 h = *(__half2*)&u;
  return __half22float2(h);
}

// ---------------- CSR build ----------------
__global__ void k_count(const int* __restrict__ dst, int* __restrict__ cnt) {
  int e = blockIdx.x * blockDim.x + threadIdx.x;
  if (e < N_EDGES) atomicAdd(&cnt[dst[e]], 1);
}

__global__ void k_dis(const int* __restrict__ cnt, float* __restrict__ dis) {
  int n = blockIdx.x * blockDim.x + threadIdx.x;
  if (n < N_NODES) dis[n] = rsqrtf((float)(cnt[n] + 1));  // +1 self loop
}

__global__ void k_partials(const int* __restrict__ cnt, int* __restrict__ bsums) {
  __shared__ int s[256];
  int i = blockIdx.x * 256 + threadIdx.x;
  s[threadIdx.x] = (i < N_NODES) ? cnt[i] : 0;
  __syncthreads();
  for (int off = 128; off > 0; off >>= 1) {
    if (threadIdx.x < off) s[threadIdx.x] += s[threadIdx.x + off];
    __syncthreads();
  }
  if (threadIdx.x == 0) bsums[blockIdx.x] = s[0];
}

__global__ void k_scan_bsums(int* __restrict__ bsums, int nb, int* __restrict__ rowptr) {
  if (threadIdx.x == 0 && blockIdx.x == 0) {
    int run = 0;
    for (int b = 0; b < nb; ++b) { int t = bsums[b]; bsums[b] = run; run += t; }
    rowptr[N_NODES] = run;
  }
}

__global__ void k_scan_write(const int* __restrict__ cnt, const int* __restrict__ bsums,
                             int* __restrict__ rowptr) {
  __shared__ int s[256];
  int i = blockIdx.x * 256 + threadIdx.x;
  int v = (i < N_NODES) ? cnt[i] : 0;
  s[threadIdx.x] = v;
  __syncthreads();
  for (int off = 1; off < 256; off <<= 1) {
    int x = 0;
    if (threadIdx.x >= off) x = s[threadIdx.x - off];
    __syncthreads();
    s[threadIdx.x] += x;
    __syncthreads();
  }
  if (i < N_NODES) rowptr[i] = bsums[blockIdx.x] + s[threadIdx.x] - v;  // exclusive
}

__global__ void k_fill(const int* __restrict__ ei, const int* __restrict__ rowptr,
                       int* __restrict__ cursor, const float* __restrict__ dis,
                       unsigned int* __restrict__ edg) {
  int e = blockIdx.x * blockDim.x + threadIdx.x;
  if (e >= N_EDGES) return;
  int s = ei[e];            // src (< 65536)
  int d = ei[N_EDGES + e];  // dst
  int pos = rowptr[d] + atomicAdd(&cursor[d], 1);
  unsigned short wb = __half_as_ushort(__float2half_rn(dis[s] * dis[d]));
  edg[pos] = (unsigned int)s | ((unsigned int)wb << 16);
}

// ---------------- GEMM: Y(fp16 slab-major) = act(X) @ W ----------------
__global__ __launch_bounds__(192) void k_gemm(const float* __restrict__ X,
                                              const float* __restrict__ Wg,
                                              const float* __restrict__ stats,
                                              const float* __restrict__ gamma,
                                              const float* __restrict__ beta,
                                              __half* __restrict__ Y) {
  __shared__ float Ws[96 * 96];
  __shared__ float Hs[48][100];
  __shared__ float sA[96], sC[96];
  const int tid = threadIdx.x;
  const int fg = tid % 24;
  const int rg = tid / 24;
  const int row0 = blockIdx.x * 48;

  for (int i = tid; i < 96 * 24; i += 192)
    *(float4*)&Ws[i * 4] = *(const float4*)&Wg[i * 4];
  if (tid < 96) {
    if (stats) {
      float mu = stats[tid] * (1.f / N_NODES);
      float var = fmaxf(stats[96 + tid] * (1.f / N_NODES) - mu * mu, 0.f);
      float a = gamma[tid] * rsqrtf(var + BN_EPS);
      sA[tid] = a;
      sC[tid] = beta[tid] - mu * a;
    } else {
      sA[tid] = 1.f;
      sC[tid] = 0.f;
    }
  }
  __syncthreads();
  const bool bn = (stats != nullptr);
  for (int i = tid; i < 48 * 24; i += 192) {
    int r = i / 24, c4 = (i % 24) * 4;
    int gr = row0 + r;
    float4 v = (gr < N_NODES) ? *(const float4*)&X[gr * 96 + c4]
                              : make_float4(0.f, 0.f, 0.f, 0.f);
    if (bn) {
      v.x = fmaxf(v.x * sA[c4] + sC[c4], 0.f);
      v.y = fmaxf(v.y * sA[c4 + 1] + sC[c4 + 1], 0.f);
      v.z = fmaxf(v.z * sA[c4 + 2] + sC[c4 + 2], 0.f);
      v.w = fmaxf(v.w * sA[c4 + 3] + sC[c4 + 3], 0.f);
    }
    *(float4*)&Hs[r][c4] = v;
  }
  __syncthreads();

  float4 acc[6];
#pragma unroll
  for (int j = 0; j < 6; ++j) acc[j] = make_float4(0.f, 0.f, 0.f, 0.f);
  const int f4 = fg * 4;
  for (int k4 = 0; k4 < 96; k4 += 4) {
    float4 w0 = *(const float4*)&Ws[(k4 + 0) * 96 + f4];
    float4 w1 = *(const float4*)&Ws[(k4 + 1) * 96 + f4];
    float4 w2 = *(const float4*)&Ws[(k4 + 2) * 96 + f4];
    float4 w3 = *(const float4*)&Ws[(k4 + 3) * 96 + f4];
#pragma unroll
    for (int j = 0; j < 6; ++j) {
      const float4 h = *(const float4*)&Hs[rg + j * 8][k4];
      acc[j].x += h.x * w0.x + h.y * w1.x + h.z * w2.x + h.w * w3.x;
      acc[j].y += h.x * w0.y + h.y * w1.y + h.z * w2.y + h.w * w3.y;
      acc[j].z += h.x * w0.z + h.y * w1.z + h.z * w2.z + h.w * w3.z;
      acc[j].w += h.x * w0.w + h.y * w1.w + h.z * w2.w + h.w * w3.w;
    }
  }
  // write fp16 slab-major: slab = fg/3, offset (fg%3)*4 halfs within 12-half row
  const int slab = fg / 3;
  const int off = (fg % 3) * 4;
#pragma unroll
  for (int j = 0; j < 6; ++j) {
    int r = row0 + rg + j * 8;
    if (r < N_NODES) {
      union { uint2 u; __half2 h[2]; } pk;
      pk.h[0] = __floats2half2_rn(acc[j].x, acc[j].y);
      pk.h[1] = __floats2half2_rn(acc[j].z, acc[j].w);
      *(uint2*)&Y[((size_t)slab * N_NODES + r) * SFEAT + off] = pk.u;
    }
  }
}

// ---------------- fused aggregation + BN-stats (slab-partitioned) ----------------
// block b: slab = b % 8 (pins slab->XCD under round-robin dispatch), chunk = b/8.
// thread = one dst node x one 12-feature slab; hw slab (1.2 MB) is L2-resident.
__global__ __launch_bounds__(256) void k_gather(const __half* __restrict__ hwh,
                                                const int* __restrict__ rowptr,
                                                const unsigned int* __restrict__ edg,
                                                const float* __restrict__ dis,
                                                float* __restrict__ agg,
                                                float* __restrict__ stats) {
  const int tid = threadIdx.x;
  const int slab = blockIdx.x & (SLABS - 1);
  const int chunk = blockIdx.x >> 3;
  const int n = chunk * 256 + tid;
  const bool valid = (n < N_NODES);
  const int nc = valid ? n : (N_NODES - 1);
  const __half* base = hwh + (size_t)slab * N_NODES * SFEAT;

  int j = rowptr[nc];
  const int e = valid ? rowptr[nc + 1] : j;

  float a[12];
  {
    float dn = dis[nc];
    float s2 = valid ? dn * dn : 0.f;  // self-loop weight; 0 for pad lanes
    const __half* rp = base + (size_t)nc * SFEAT;
    uint2 A = *(const uint2*)rp;
    uint2 B = *(const uint2*)(rp + 4);
    uint2 C = *(const uint2*)(rp + 8);
    float2 f0 = h2f(A.x), f1 = h2f(A.y), f2 = h2f(B.x);
    float2 f3 = h2f(B.y), f4 = h2f(C.x), f5 = h2f(C.y);
    a[0] = f0.x * s2; a[1] = f0.y * s2; a[2] = f1.x * s2; a[3] = f1.y * s2;
    a[4] = f2.x * s2; a[5] = f2.y * s2; a[6] = f3.x * s2; a[7] = f3.y * s2;
    a[8] = f4.x * s2; a[9] = f4.y * s2; a[10] = f5.x * s2; a[11] = f5.y * s2;
  }

  while (__ballot(j < e)) {
    if (j < e) {
      unsigned int er = edg[j];
      int src = (int)(er & 0xFFFFu);
      float w = __half2float(__ushort_as_half((unsigned short)(er >> 16)));
      const __half* rp = base + (size_t)src * SFEAT;
      uint2 A = *(const uint2*)rp;
      uint2 B = *(const uint2*)(rp + 4);
      uint2 C = *(const uint2*)(rp + 8);
      float2 f0 = h2f(A.x), f1 = h2f(A.y), f2 = h2f(B.x);
      float2 f3 = h2f(B.y), f4 = h2f(C.x), f5 = h2f(C.y);
      a[0] = fmaf(w, f0.x, a[0]);  a[1] = fmaf(w, f0.y, a[1]);
      a[2] = fmaf(w, f1.x, a[2]);  a[3] = fmaf(w, f1.y, a[3]);
      a[4] = fmaf(w, f2.x, a[4]);  a[5] = fmaf(w, f2.y, a[5]);
      a[6] = fmaf(w, f3.x, a[6]);  a[7] = fmaf(w, f3.y, a[7]);
      a[8] = fmaf(w, f4.x, a[8]);  a[9] = fmaf(w, f4.y, a[9]);
      a[10] = fmaf(w, f5.x, a[10]); a[11] = fmaf(w, f5.y, a[11]);
      ++j;
    }
  }

  if (valid) {
    float4* ap = (float4*)&agg[(size_t)n * DD + slab * SFEAT];
    ap[0] = make_float4(a[0], a[1], a[2], a[3]);
    ap[1] = make_float4(a[4], a[5], a[6], a[7]);
    ap[2] = make_float4(a[8], a[9], a[10], a[11]);
  }

  // BN stats: wave-reduce each of 12 channels (sum, sumsq), lane0 -> global atomic
  const int lane = tid & 63;
#pragma unroll
  for (int i = 0; i < 12; ++i) {
    float v = a[i];
    float q = a[i] * a[i];
#pragma unroll
    for (int off = 32; off > 0; off >>= 1) {
      v += __shfl_down(v, off);
      q += __shfl_down(q, off);
    }
    if (lane == 0) {
      atomAddF(&stats[slab * SFEAT + i], v);
      atomAddF(&stats[96 + slab * SFEAT + i], q);
    }
  }
}

// ---------------- pooling: final BN+ReLU + segment-sum over sorted batch ----------------
__global__ __launch_bounds__(192) void k_pool(const float* __restrict__ h,
                                              const float* __restrict__ stats,
                                              const float* __restrict__ gamma,
                                              const float* __restrict__ beta,
                                              const int* __restrict__ batch,
                                              float* __restrict__ pool) {
  __shared__ float sA[96], sC[96];
  const int tid = threadIdx.x;
  if (tid < 96) {
    float mu = stats[tid] * (1.f / N_NODES);
    float var = fmaxf(stats[96 + tid] * (1.f / N_NODES) - mu * mu, 0.f);
    float a = gamma[tid] * rsqrtf(var + BN_EPS);
    sA[tid] = a;
    sC[tid] = beta[tid] - mu * a;
  }
  __syncthreads();
  const int chain = blockIdx.x * 8 + tid / 24;
  const int q4 = (tid % 24) * 4;
  int n0 = chain * 32;
  if (n0 >= N_NODES) return;
  int n1 = min(n0 + 32, N_NODES);
  float A0 = sA[q4], A1 = sA[q4 + 1], A2 = sA[q4 + 2], A3 = sA[q4 + 3];
  float C0 = sC[q4], C1 = sC[q4 + 1], C2 = sC[q4 + 2], C3 = sC[q4 + 3];
  int cur = batch[n0];
  float4 acc = make_float4(0.f, 0.f, 0.f, 0.f);
  for (int n = n0; n < n1; ++n) {
    int g = batch[n];
    if (g != cur) {
      float* p = &pool[cur * 96 + q4];
      atomAddF(p, acc.x); atomAddF(p + 1, acc.y);
      atomAddF(p + 2, acc.z); atomAddF(p + 3, acc.w);
      acc = make_float4(0.f, 0.f, 0.f, 0.f);
      cur = g;
    }
    const float4 v = *(const float4*)&h[n * 96 + q4];
    acc.x += fmaxf(v.x * A0 + C0, 0.f);
    acc.y += fmaxf(v.y * A1 + C1, 0.f);
    acc.z += fmaxf(v.z * A2 + C2, 0.f);
    acc.w += fmaxf(v.w * A3 + C3, 0.f);
  }
  float* p = &pool[cur * 96 + q4];
  atomAddF(p, acc.x); atomAddF(p + 1, acc.y);
  atomAddF(p + 2, acc.z); atomAddF(p + 3, acc.w);
}

__global__ void k_gcount(const int* __restrict__ batch, int* __restrict__ gcnt) {
  int n = blockIdx.x * blockDim.x + threadIdx.x;
  if (n < N_NODES) atomicAdd(&gcnt[batch[n]], 1);
}

__global__ void k_out(const float* __restrict__ pool, const int* __restrict__ gcnt,
                      float* __restrict__ out) {
  int t = blockIdx.x * blockDim.x + threadIdx.x;
  if (t >= N_GRAPHS * 96) return;
  int g = t / 96;
  int c = gcnt[g];
  if (c < 1) c = 1;
  out[t] = pool[t] / (float)c;
}

extern "C" void kernel_launch(void* const* d_in, const int* in_sizes, int n_in,
                              void* d_out, int out_size, void* d_ws, size_t ws_size,
                              hipStream_t stream) {
  const float* x     = (const float*)d_in[0];
  const int*   ei    = (const int*)d_in[1];   // [2, E]: src row then dst row
  const int*   batch = (const int*)d_in[2];
  const float* W     = (const float*)d_in[3]; // [4,96,96]
  // d_in[4] = b : cancels exactly through BatchNorm, unused
  const float* gamma = (const float*)d_in[5]; // [4,96]
  const float* beta  = (const float*)d_in[6];
  float* out = (float*)d_out;

  float* ws = (float*)d_ws;
  int*   cnt    = (int*)(ws + O_CNT);
  float* stats  = ws + O_STATS;
  float* pool   = ws + O_POOL;
  int*   gcnt   = (int*)(ws + O_GCNT);
  int*   rowptr = (int*)(ws + O_ROWPTR);
  float* dis    = ws + O_DIS;
  int*   bsums  = (int*)(ws + O_BSUMS);
  unsigned int* edg = (unsigned int*)(ws + O_EDGE);
  __half* hwh   = (__half*)(ws + O_HWH);
  float* P      = ws + O_P;  // agg (fp32)

  hipMemsetAsync(d_ws, 0, ZERO_END * sizeof(float), stream);

  const int eb = (N_EDGES + 255) / 256;
  const int nb = (N_NODES + 255) / 256;  // 196
  k_count<<<eb, 256, 0, stream>>>(ei + N_EDGES, cnt);
  k_dis<<<nb, 256, 0, stream>>>(cnt, dis);
  k_partials<<<nb, 256, 0, stream>>>(cnt, bsums);
  k_scan_bsums<<<1, 64, 0, stream>>>(bsums, nb, rowptr);
  k_scan_write<<<nb, 256, 0, stream>>>(cnt, bsums, rowptr);
  hipMemsetAsync(cnt, 0, N_NODES * sizeof(int), stream);  // reuse as fill cursors
  k_fill<<<eb, 256, 0, stream>>>(ei, rowptr, cnt, dis, edg);

  const int gemmb = (N_NODES + 47) / 48;   // 1042
  const int gatherb = SLABS * nb;          // 8 * 196 = 1568

  const float* hin = x;
  for (int l = 0; l < NLAYER; ++l) {
    const float* st = (l == 0) ? nullptr : (stats + (l - 1) * 192);
    const float* ga = (l == 0) ? nullptr : (gamma + (l - 1) * 96);
    const float* be = (l == 0) ? nullptr : (beta + (l - 1) * 96);
    k_gemm<<<gemmb, 192, 0, stream>>>(hin, W + l * 96 * 96, st, ga, be, hwh);
    k_gather<<<gatherb, 256, 0, stream>>>(hwh, rowptr, edg, dis, P, stats + l * 192);
    hin = P;
  }

  const int poolb = ((N_NODES + 31) / 32 + 7) / 8;  // 196
  k_pool<<<poolb, 192, 0, stream>>>(P, stats + 3 * 192, gamma + 3 * 96, beta + 3 * 96,
                                    batch, pool);
  k_gcount<<<nb, 256, 0, stream>>>(batch, gcnt);
  k_out<<<(N_GRAPHS * 96 + 255) / 256, 256, 0, stream>>>(pool, gcnt, out);
}

// Round 5
// 681.167 us; speedup vs baseline: 2.9152x; 2.9152x over previous
//
#include <hip/hip_runtime.h>
#include <hip/hip_bf16.h>
#include <hip/hip_fp16.h>

#define N_NODES 50000
#define N_EDGES 800000
#define DD 96
#define NLAYER 4
#define N_GRAPHS 256
#define BN_EPS 1e-5f
#define SLABS 8
#define SFEAT 12  // halfs per slab row (24 B); SLABS*SFEAT = 96

// ---------------- workspace layout (units: 4-byte elements) ----------------
enum : size_t {
  O_CNT    = 0,                        // int[N_NODES]
  O_STATS  = O_CNT + N_NODES,          // float[4*192]  (sum, sumsq per layer)
  O_POOL   = O_STATS + 4 * 192,        // float[N_GRAPHS*96]
  O_GCNT   = O_POOL + N_GRAPHS * DD,   // int[N_GRAPHS]
  ZERO_END = O_GCNT + N_GRAPHS,
  O_ROWPTR = ZERO_END,                 // int[N_NODES+1]
  O_DIS    = O_ROWPTR + N_NODES + 1,   // float[N_NODES]
  O_BSUMS  = O_DIS + N_NODES,          // int[256]
  O_EDGE   = O_BSUMS + 256,            // uint[N_EDGES]: src | half(w)<<16
  O_HWH    = (O_EDGE + N_EDGES + 3) & ~size_t(3),  // half[8][50000][12] = 9.6 MB
  O_P      = O_HWH + (size_t)SLABS * N_NODES * SFEAT / 2,  // float[N_NODES*96] agg
  WS_ELEMS = O_P + (size_t)N_NODES * DD
};

__device__ __forceinline__ void atomAddF(float* p, float v) {
  unsafeAtomicAdd(p, v);  // native fp32 atomic add
}

__device__ __forceinline__ float2 h2f(unsigned int u) {
  __half2 h = *(__half2*)&u;
  return __half22float2(h);
}

// ---------------- CSR build ----------------
__global__ void k_count(const int* __restrict__ dst, int* __restrict__ cnt) {
  int e = blockIdx.x * blockDim.x + threadIdx.x;
  if (e < N_EDGES) atomicAdd(&cnt[dst[e]], 1);
}

__global__ void k_dis(const int* __restrict__ cnt, float* __restrict__ dis) {
  int n = blockIdx.x * blockDim.x + threadIdx.x;
  if (n < N_NODES) dis[n] = rsqrtf((float)(cnt[n] + 1));  // +1 self loop
}

__global__ void k_partials(const int* __restrict__ cnt, int* __restrict__ bsums) {
  __shared__ int s[256];
  int i = blockIdx.x * 256 + threadIdx.x;
  s[threadIdx.x] = (i < N_NODES) ? cnt[i] : 0;
  __syncthreads();
  for (int off = 128; off > 0; off >>= 1) {
    if (threadIdx.x < off) s[threadIdx.x] += s[threadIdx.x + off];
    __syncthreads();
  }
  if (threadIdx.x == 0) bsums[blockIdx.x] = s[0];
}

__global__ void k_scan_bsums(int* __restrict__ bsums, int nb, int* __restrict__ rowptr) {
  if (threadIdx.x == 0 && blockIdx.x == 0) {
    int run = 0;
    for (int b = 0; b < nb; ++b) { int t = bsums[b]; bsums[b] = run; run += t; }
    rowptr[N_NODES] = run;
  }
}

__global__ void k_scan_write(const int* __restrict__ cnt, const int* __restrict__ bsums,
                             int* __restrict__ rowptr) {
  __shared__ int s[256];
  int i = blockIdx.x * 256 + threadIdx.x;
  int v = (i < N_NODES) ? cnt[i] : 0;
  s[threadIdx.x] = v;
  __syncthreads();
  for (int off = 1; off < 256; off <<= 1) {
    int x = 0;
    if (threadIdx.x >= off) x = s[threadIdx.x - off];
    __syncthreads();
    s[threadIdx.x] += x;
    __syncthreads();
  }
  if (i < N_NODES) rowptr[i] = bsums[blockIdx.x] + s[threadIdx.x] - v;  // exclusive
}

__global__ void k_fill(const int* __restrict__ ei, const int* __restrict__ rowptr,
                       int* __restrict__ cursor, const float* __restrict__ dis,
                       unsigned int* __restrict__ edg) {
  int e = blockIdx.x * blockDim.x + threadIdx.x;
  if (e >= N_EDGES) return;
  int s = ei[e];            // src (< 65536)
  int d = ei[N_EDGES + e];  // dst
  int pos = rowptr[d] + atomicAdd(&cursor[d], 1);
  unsigned short wb = __half_as_ushort(__float2half_rn(dis[s] * dis[d]));
  edg[pos] = (unsigned int)s | ((unsigned int)wb << 16);
}

// ---------------- GEMM: Y(fp16 slab-major) = act(X) @ W ----------------
__global__ __launch_bounds__(192) void k_gemm(const float* __restrict__ X,
                                              const float* __restrict__ Wg,
                                              const float* __restrict__ stats,
                                              const float* __restrict__ gamma,
                                              const float* __restrict__ beta,
                                              __half* __restrict__ Y) {
  __shared__ float Ws[96 * 96];
  __shared__ float Hs[48][100];
  __shared__ float sA[96], sC[96];
  const int tid = threadIdx.x;
  const int fg = tid % 24;
  const int rg = tid / 24;
  const int row0 = blockIdx.x * 48;

  for (int i = tid; i < 96 * 24; i += 192)
    *(float4*)&Ws[i * 4] = *(const float4*)&Wg[i * 4];
  if (tid < 96) {
    if (stats) {
      float mu = stats[tid] * (1.f / N_NODES);
      float var = fmaxf(stats[96 + tid] * (1.f / N_NODES) - mu * mu, 0.f);
      float a = gamma[tid] * rsqrtf(var + BN_EPS);
      sA[tid] = a;
      sC[tid] = beta[tid] - mu * a;
    } else {
      sA[tid] = 1.f;
      sC[tid] = 0.f;
    }
  }
  __syncthreads();
  const bool bn = (stats != nullptr);
  for (int i = tid; i < 48 * 24; i += 192) {
    int r = i / 24, c4 = (i % 24) * 4;
    int gr = row0 + r;
    float4 v = (gr < N_NODES) ? *(const float4*)&X[gr * 96 + c4]
                              : make_float4(0.f, 0.f, 0.f, 0.f);
    if (bn) {
      v.x = fmaxf(v.x * sA[c4] + sC[c4], 0.f);
      v.y = fmaxf(v.y * sA[c4 + 1] + sC[c4 + 1], 0.f);
      v.z = fmaxf(v.z * sA[c4 + 2] + sC[c4 + 2], 0.f);
      v.w = fmaxf(v.w * sA[c4 + 3] + sC[c4 + 3], 0.f);
    }
    *(float4*)&Hs[r][c4] = v;
  }
  __syncthreads();

  float4 acc[6];
#pragma unroll
  for (int j = 0; j < 6; ++j) acc[j] = make_float4(0.f, 0.f, 0.f, 0.f);
  const int f4 = fg * 4;
  for (int k4 = 0; k4 < 96; k4 += 4) {
    float4 w0 = *(const float4*)&Ws[(k4 + 0) * 96 + f4];
    float4 w1 = *(const float4*)&Ws[(k4 + 1) * 96 + f4];
    float4 w2 = *(const float4*)&Ws[(k4 + 2) * 96 + f4];
    float4 w3 = *(const float4*)&Ws[(k4 + 3) * 96 + f4];
#pragma unroll
    for (int j = 0; j < 6; ++j) {
      const float4 h = *(const float4*)&Hs[rg + j * 8][k4];
      acc[j].x += h.x * w0.x + h.y * w1.x + h.z * w2.x + h.w * w3.x;
      acc[j].y += h.x * w0.y + h.y * w1.y + h.z * w2.y + h.w * w3.y;
      acc[j].z += h.x * w0.z + h.y * w1.z + h.z * w2.z + h.w * w3.z;
      acc[j].w += h.x * w0.w + h.y * w1.w + h.z * w2.w + h.w * w3.w;
    }
  }
  // write fp16 slab-major: slab = fg/3, offset (fg%3)*4 halfs within 12-half row
  const int slab = fg / 3;
  const int off = (fg % 3) * 4;
#pragma unroll
  for (int j = 0; j < 6; ++j) {
    int r = row0 + rg + j * 8;
    if (r < N_NODES) {
      union { uint2 u; __half2 h[2]; } pk;
      pk.h[0] = __floats2half2_rn(acc[j].x, acc[j].y);
      pk.h[1] = __floats2half2_rn(acc[j].z, acc[j].w);
      *(uint2*)&Y[((size_t)slab * N_NODES + r) * SFEAT + off] = pk.u;
    }
  }
}

// ---------------- fused aggregation + BN-stats (slab-partitioned, row-shared) ----
// block b: slab = b & 7 (pins slab->XCD under round-robin dispatch), chunk = b>>3.
// Group = 6 lanes per dst node; lane owns 2 fp16 channels (4 B of the 24 B row).
// Wave = 10 nodes (lanes 60-63 idle). 8-wide branchless edge unroll -> 16 loads
// in flight per lane; all 6 lanes of a group read the SAME source row (line share).
__global__ __launch_bounds__(256) void k_gather(const __half* __restrict__ hwh,
                                                const int* __restrict__ rowptr,
                                                const unsigned int* __restrict__ edg,
                                                const float* __restrict__ dis,
                                                float* __restrict__ agg,
                                                float* __restrict__ stats) {
  __shared__ float sred[24];
  const int tid = threadIdx.x;
  const int slab = blockIdx.x & (SLABS - 1);
  const int chunk = blockIdx.x >> 3;
  const int wave = tid >> 6;
  const int lane = tid & 63;
  const int g = lane / 6;     // 0..10 (g==10 -> idle)
  const int ch = lane - g * 6; // channel pair index 0..5
  const int n = chunk * 40 + wave * 10 + g;
  const bool valid = (g < 10) && (n < N_NODES);
  const int nc = valid ? n : 0;

  const unsigned int* slabU =
      (const unsigned int*)(hwh) + (size_t)slab * N_NODES * (SFEAT / 2);

  if (tid < 24) sred[tid] = 0.f;

  const int js = valid ? rowptr[nc] : 0;
  const int je = valid ? rowptr[nc + 1] : 0;

  float a0 = 0.f, a1 = 0.f;
  if (valid) {
    float dn = dis[nc];
    float s2 = dn * dn;  // self-loop weight
    float2 f = h2f(slabU[nc * 6 + ch]);
    a0 = f.x * s2;
    a1 = f.y * s2;
  }

  for (int j = js; j < je; j += 8) {
    unsigned int ew[8];
    unsigned int rv[8];
#pragma unroll
    for (int k = 0; k < 8; ++k) {
      int jk = j + k;
      int jc = jk < je ? jk : (je - 1);  // clamp to hot line
      ew[k] = edg[jc];
    }
#pragma unroll
    for (int k = 0; k < 8; ++k)
      rv[k] = slabU[(int)(ew[k] & 0xFFFFu) * 6 + ch];
#pragma unroll
    for (int k = 0; k < 8; ++k) {
      float w = (j + k < je)
                    ? __half2float(__ushort_as_half((unsigned short)(ew[k] >> 16)))
                    : 0.f;
      float2 f = h2f(rv[k]);
      a0 = fmaf(w, f.x, a0);
      a1 = fmaf(w, f.y, a1);
    }
  }

  if (valid) {
    *(float2*)&agg[(size_t)n * DD + slab * SFEAT + ch * 2] = make_float2(a0, a1);
  }

  __syncthreads();
  if (valid) {
    atomAddF(&sred[ch * 2], a0);
    atomAddF(&sred[ch * 2 + 1], a1);
    atomAddF(&sred[12 + ch * 2], a0 * a0);
    atomAddF(&sred[13 + ch * 2], a1 * a1);
  }
  __syncthreads();
  if (tid < 24) {
    int c = (tid < 12) ? (slab * SFEAT + tid) : (96 + slab * SFEAT + tid - 12);
    atomAddF(&stats[c], sred[tid]);
  }
}

// ---------------- pooling: final BN+ReLU + segment-sum over sorted batch ----------------
__global__ __launch_bounds__(192) void k_pool(const float* __restrict__ h,
                                              const float* __restrict__ stats,
                                              const float* __restrict__ gamma,
                                              const float* __restrict__ beta,
                                              const int* __restrict__ batch,
                                              float* __restrict__ pool) {
  __shared__ float sA[96], sC[96];
  const int tid = threadIdx.x;
  if (tid < 96) {
    float mu = stats[tid] * (1.f / N_NODES);
    float var = fmaxf(stats[96 + tid] * (1.f / N_NODES) - mu * mu, 0.f);
    float a = gamma[tid] * rsqrtf(var + BN_EPS);
    sA[tid] = a;
    sC[tid] = beta[tid] - mu * a;
  }
  __syncthreads();
  const int chain = blockIdx.x * 8 + tid / 24;
  const int q4 = (tid % 24) * 4;
  int n0 = chain * 32;
  if (n0 >= N_NODES) return;
  int n1 = min(n0 + 32, N_NODES);
  float A0 = sA[q4], A1 = sA[q4 + 1], A2 = sA[q4 + 2], A3 = sA[q4 + 3];
  float C0 = sC[q4], C1 = sC[q4 + 1], C2 = sC[q4 + 2], C3 = sC[q4 + 3];
  int cur = batch[n0];
  float4 acc = make_float4(0.f, 0.f, 0.f, 0.f);
  for (int n = n0; n < n1; ++n) {
    int g = batch[n];
    if (g != cur) {
      float* p = &pool[cur * 96 + q4];
      atomAddF(p, acc.x); atomAddF(p + 1, acc.y);
      atomAddF(p + 2, acc.z); atomAddF(p + 3, acc.w);
      acc = make_float4(0.f, 0.f, 0.f, 0.f);
      cur = g;
    }
    const float4 v = *(const float4*)&h[n * 96 + q4];
    acc.x += fmaxf(v.x * A0 + C0, 0.f);
    acc.y += fmaxf(v.y * A1 + C1, 0.f);
    acc.z += fmaxf(v.z * A2 + C2, 0.f);
    acc.w += fmaxf(v.w * A3 + C3, 0.f);
  }
  float* p = &pool[cur * 96 + q4];
  atomAddF(p, acc.x); atomAddF(p + 1, acc.y);
  atomAddF(p + 2, acc.z); atomAddF(p + 3, acc.w);
}

__global__ void k_gcount(const int* __restrict__ batch, int* __restrict__ gcnt) {
  int n = blockIdx.x * blockDim.x + threadIdx.x;
  if (n < N_NODES) atomicAdd(&gcnt[batch[n]], 1);
}

__global__ void k_out(const float* __restrict__ pool, const int* __restrict__ gcnt,
                      float* __restrict__ out) {
  int t = blockIdx.x * blockDim.x + threadIdx.x;
  if (t >= N_GRAPHS * 96) return;
  int g = t / 96;
  int c = gcnt[g];
  if (c < 1) c = 1;
  out[t] = pool[t] / (float)c;
}

extern "C" void kernel_launch(void* const* d_in, const int* in_sizes, int n_in,
                              void* d_out, int out_size, void* d_ws, size_t ws_size,
                              hipStream_t stream) {
  const float* x     = (const float*)d_in[0];
  const int*   ei    = (const int*)d_in[1];   // [2, E]: src row then dst row
  const int*   batch = (const int*)d_in[2];
  const float* W     = (const float*)d_in[3]; // [4,96,96]
  // d_in[4] = b : cancels exactly through BatchNorm, unused
  const float* gamma = (const float*)d_in[5]; // [4,96]
  const float* beta  = (const float*)d_in[6];
  float* out = (float*)d_out;

  float* ws = (float*)d_ws;
  int*   cnt    = (int*)(ws + O_CNT);
  float* stats  = ws + O_STATS;
  float* pool   = ws + O_POOL;
  int*   gcnt   = (int*)(ws + O_GCNT);
  int*   rowptr = (int*)(ws + O_ROWPTR);
  float* dis    = ws + O_DIS;
  int*   bsums  = (int*)(ws + O_BSUMS);
  unsigned int* edg = (unsigned int*)(ws + O_EDGE);
  __half* hwh   = (__half*)(ws + O_HWH);
  float* P      = ws + O_P;  // agg (fp32)

  hipMemsetAsync(d_ws, 0, ZERO_END * sizeof(float), stream);

  const int eb = (N_EDGES + 255) / 256;
  const int nb = (N_NODES + 255) / 256;  // 196
  k_count<<<eb, 256, 0, stream>>>(ei + N_EDGES, cnt);
  k_dis<<<nb, 256, 0, stream>>>(cnt, dis);
  k_partials<<<nb, 256, 0, stream>>>(cnt, bsums);
  k_scan_bsums<<<1, 64, 0, stream>>>(bsums, nb, rowptr);
  k_scan_write<<<nb, 256, 0, stream>>>(cnt, bsums, rowptr);
  hipMemsetAsync(cnt, 0, N_NODES * sizeof(int), stream);  // reuse as fill cursors
  k_fill<<<eb, 256, 0, stream>>>(ei, rowptr, cnt, dis, edg);

  const int gemmb = (N_NODES + 47) / 48;            // 1042
  const int gatherb = SLABS * ((N_NODES + 39) / 40); // 8 * 1250 = 10000

  const float* hin = x;
  for (int l = 0; l < NLAYER; ++l) {
    const float* st = (l == 0) ? nullptr : (stats + (l - 1) * 192);
    const float* ga = (l == 0) ? nullptr : (gamma + (l - 1) * 96);
    const float* be = (l == 0) ? nullptr : (beta + (l - 1) * 96);
    k_gemm<<<gemmb, 192, 0, stream>>>(hin, W + l * 96 * 96, st, ga, be, hwh);
    k_gather<<<gatherb, 256, 0, stream>>>(hwh, rowptr, edg, dis, P, stats + l * 192);
    hin = P;
  }

  const int poolb = ((N_NODES + 31) / 32 + 7) / 8;  // 196
  k_pool<<<poolb, 192, 0, stream>>>(P, stats + 3 * 192, gamma + 3 * 96, beta + 3 * 96,
                                    batch, pool);
  k_gcount<<<nb, 256, 0, stream>>>(batch, gcnt);
  k_out<<<(N_GRAPHS * 96 + 255) / 256, 256, 0, stream>>>(pool, gcnt, out);
}